// Round 12
// baseline (271.057 us; speedup 1.0000x reference)
//
#include <hip/hip_runtime.h>
#include <hip/hip_bf16.h>
#include <stdint.h>

#define NSTEP   32
#define BATCH   65536
#define NTHR    512
#define RPB     256          /* rows per block = 8 waves x 32 */
#define DELTA_F (1.0f/32.0f)
#define LN2PI_F 1.83787706640934534f

// R31: R30 champion (199.1us) MINUS all s_setprio — clean A/B of the one
// inherited, never-isolated knob. T5 (setprio) requires wave role diversity;
// this barrier-free 2-wave/SIMD structure is near-lockstep (R24: narrowing
// setprio -4%; m190: broad setprio -1.5% on lockstep GEMM). Symmetric boost
// = null arbitration signal + distortion. Everything else byte-identical.
#define RB1 208              /* W1T row: 104 u16 (80 used: a0-15 sigma, s16-79) */
#define RB2 304              /* W2T row: 152 u16 (128 used: W2 sigma) */
#define RB3 272              /* W3C row: 136 u16 (128 used; rows 16..31 zero) */
#define OFF_W1 0             /* 128*208 = 26624 */
#define OFF_W2 26624         /* 128*304 = 38912 */
#define OFF_W3 65536         /* 32*272  = 8704  */
#define OFF_HI 74240         /* 32*4*2*16 f32 = 16384 */
#define OFF_FI 90624         /* 4*2*16 f32 = 512 */
#define LDS_BYTES 91136      /* 1 block/CU */

typedef __attribute__((ext_vector_type(8)))  short    s16x8;
typedef __attribute__((ext_vector_type(8)))  __bf16   bf16x8;
typedef __attribute__((ext_vector_type(4)))  float    f32x4;
typedef __attribute__((ext_vector_type(16))) float    f32x16;
typedef __attribute__((ext_vector_type(4)))  int      i32x4;
typedef __attribute__((ext_vector_type(4)))  unsigned u32x4;

#define Z16 ((f32x16){0,0,0,0,0,0,0,0,0,0,0,0,0,0,0,0})

static __device__ __forceinline__ f32x16 mfma32(s16x8 a, s16x8 b, f32x16 c){
    return __builtin_amdgcn_mfma_f32_32x32x16_bf16(
        __builtin_bit_cast(bf16x8, a), __builtin_bit_cast(bf16x8, b), c, 0, 0, 0);
}

static __device__ __forceinline__ unsigned short f2bf(float f){
    union { float f; unsigned u; } v; v.f = f;
    unsigned u = v.u + 0x7fffu + ((v.u >> 16) & 1u);   // RNE
    return (unsigned short)(u >> 16);
}

static __device__ __forceinline__ unsigned cvtpk(float lo, float hi){
    unsigned r;
    asm("v_cvt_pk_bf16_f32 %0, %1, %2" : "=v"(r) : "v"(lo), "v"(hi));
    return r;
}

// permlane32_swap (cold paths only: Hutchinson reduce + final asq)
static __device__ __forceinline__ void pswap(unsigned &a, unsigned &b){
    auto r = __builtin_amdgcn_permlane32_swap((int)a, (int)b, false, false);
    a = (unsigned)r[0]; b = (unsigned)r[1];
}

// sigma: swap bits 2 and 3 within each 16-block of the k index (self-inverse)
static __device__ __forceinline__ int sgk(int k){
    return (k & ~12) | ((k & 4) << 1) | ((k & 8) >> 1);
}

static __device__ __forceinline__ s16x8 pconv(i32x4 u0, i32x4 u1){
    const unsigned P = 0x3F80u, M = 0xBF80u;
    u32x4 d;
    d[0] = (u0[0] ? P : M) | ((u0[1] ? P : M) << 16);
    d[1] = (u0[2] ? P : M) | ((u0[3] ? P : M) << 16);
    d[2] = (u1[0] ? P : M) | ((u1[1] ? P : M) << 16);
    d[3] = (u1[2] ? P : M) | ((u1[3] ? P : M) << 16);
    return __builtin_bit_cast(s16x8, d);
}

// relu+mask pack of a 32x32 C-tile (16 f32) + tangent -> two k-tile B-frags
// each. NO cross-lane ops: sigma-staged weights absorb the lane->k mapping.
static __device__ __forceinline__ void pack_tr(const f32x16 h, const f32x16 tt,
        s16x8* bA, s16x8* bB, s16x8* tA, s16x8* tB){
    unsigned Ph[8], Pt[8];
#pragma unroll
    for (int q = 0; q < 8; ++q){
        float h0 = h[2*q], h1 = h[2*q+1];
        float r0 = h0 > 0.f ? h0 : 0.f,      r1 = h1 > 0.f ? h1 : 0.f;
        float s0 = h0 > 0.f ? tt[2*q] : 0.f, s1 = h1 > 0.f ? tt[2*q+1] : 0.f;
        Ph[q] = cvtpk(r0, r1);
        Pt[q] = cvtpk(s0, s1);
    }
    *bA = __builtin_bit_cast(s16x8, (u32x4){Ph[0], Ph[1], Ph[2], Ph[3]});
    *bB = __builtin_bit_cast(s16x8, (u32x4){Ph[4], Ph[5], Ph[6], Ph[7]});
    *tA = __builtin_bit_cast(s16x8, (u32x4){Pt[0], Pt[1], Pt[2], Pt[3]});
    *tB = __builtin_bit_cast(s16x8, (u32x4){Pt[4], Pt[5], Pt[6], Pt[7]});
}

__global__ __launch_bounds__(NTHR, 2)
void cfm_kernel(const float* __restrict__ s_g,
                const float* __restrict__ a0_g,
                const int*   __restrict__ rad_g,
                const float* __restrict__ W1g, const float* __restrict__ b1g,
                const float* __restrict__ W2g, const float* __restrict__ b2g,
                const float* __restrict__ W3g, const float* __restrict__ b3g,
                float* __restrict__ out_g)
{
    extern __shared__ char lds[];
    const int tid  = threadIdx.x;
    const int lane = tid & 63;
    const int wv   = tid >> 6;     // 0..7
    const int c32  = lane & 31;    // batch col within wave tile
    const int hi   = lane >> 5;    // k-half

    unsigned short* W1t = (unsigned short*)(lds + OFF_W1);
    unsigned short* W2t = (unsigned short*)(lds + OFF_W2);
    unsigned short* W3c = (unsigned short*)(lds + OFF_W3);
    float* HIt = (float*)(lds + OFF_HI);
    float* FIt = (float*)(lds + OFF_FI);

    // ------------- stage weights ONCE (sigma-permuted k-columns) -------------
    for (int idx = tid; idx < 128*104; idx += NTHR){
        int n = idx / 104, k = idx % 104;
        float v = 0.f;
        if (k < 16)       v = W1g[sgk(k)*128 + n];          // a-cols: sigma
        else if (k < 80)  v = W1g[k*128 + n];               // s-cols: identity
        W1t[n*104 + k] = f2bf(v);
    }
    for (int idx = tid; idx < 128*152; idx += NTHR){
        int n = idx / 152, k = idx % 152;
        float v = (k < 128) ? W2g[sgk(k)*128 + n] : 0.f;    // sigma
        W2t[n*152 + k] = f2bf(v);
    }
    for (int idx = tid; idx < 32*136; idx += NTHR){
        int m = idx / 136, k = idx % 136;
        float v = 0.f;
        if (m < 16 && k < 128){
            int pk = sgk(k);                                // sigma
            v = W3g[pk*32 + m] + W3g[pk*32 + 16 + m];
        }
        W3c[m*136 + k] = f2bf(v);
    }
    // HI table: [t][M][hi][16 r-ordered] = b1[m] + tmid(t)*W8[m], exact f32
    for (int idx = tid; idx < 32*4*2*16; idx += NTHR){
        int e  = idx & 15;
        int h2 = (idx >> 4) & 1;
        int M  = (idx >> 5) & 3;
        int t  = idx >> 7;
        int m  = 32*M + (e & 3) + 8*(e >> 2) + 4*h2;
        float tmid = ((float)t + 0.5f) * DELTA_F;
        HIt[idx] = b1g[m] + tmid * W1g[80*128 + m];
    }
    // FI table: [Mo][hi][16 r-ordered] = b2[m], exact f32
    if (tid < 128){
        int e  = tid & 15;
        int h2 = (tid >> 4) & 1;
        int Mo = tid >> 5;
        int m  = 32*Mo + (e & 3) + 8*(e >> 2) + 4*h2;
        FIt[tid] = b2g[m];
    }
    __syncthreads();

    // per-lane LDS bases (A-operand rows = c32; +hi*16 = k-half)
    const char* pW1 = lds + OFF_W1 + c32*RB1 + hi*16;
    const char* pW2 = lds + OFF_W2 + c32*RB2 + hi*16;
    const char* pW3 = lds + OFF_W3 + c32*RB3 + hi*16;
    const char* pHI = lds + OFF_HI + hi*64;   // + t*512 + M*128
    const char* pFI = lds + OFF_FI + hi*64;   // + Mo*128

    const int row = blockIdx.x * RPB + wv*32 + c32;

    // ---- X s-tiles (static over steps): tile K holds x[16K+8hi+j] ----
    const float* srow = s_g + (size_t)row * 64;
    s16x8 xk1, xk2, xk3, xk4;
    {
        auto mk_s = [&](int K)->s16x8{
            f32x4 u = *(const f32x4*)(srow + 16*(K-1) + 8*hi);
            f32x4 w = *(const f32x4*)(srow + 16*(K-1) + 8*hi + 4);
            return __builtin_bit_cast(s16x8, (u32x4){
                cvtpk(u[0],u[1]), cvtpk(u[2],u[3]), cvtpk(w[0],w[1]), cvtpk(w[2],w[3])});
        };
        xk1 = mk_s(1); xk2 = mk_s(2); xk3 = mk_s(3); xk4 = mk_s(4);
    }

    // a in f32: av0 = a[4hi+j], av1 = a[8+4hi+j]  (matches C-layout rows r0..3 / r4..7)
    f32x4 av0 = *(const f32x4*)(a0_g + (size_t)row*16 + 4*hi);
    f32x4 av1 = *(const f32x4*)(a0_g + (size_t)row*16 + 8 + 4*hi);

    // xk0 (a-tile B-frag): sigma-staged W1 a-cols -> pure in-lane pack
    auto mk_a = [&]()->s16x8{
        return __builtin_bit_cast(s16x8, (u32x4){
            cvtpk(av0[0],av0[1]), cvtpk(av0[2],av0[3]),
            cvtpk(av1[0],av1[1]), cvtpk(av1[2],av1[3])});
    };
    s16x8 xk0 = mk_a();

    // b3 combined (v_c + r), f32 per-lane: rows {4hi+j} and {8+4hi+j}
    f32x4 b3c0, b3c1;
    {
        f32x4 p0 = *(const f32x4*)(b3g + 4*hi);
        f32x4 p1 = *(const f32x4*)(b3g + 16 + 4*hi);
        f32x4 p2 = *(const f32x4*)(b3g + 8 + 4*hi);
        f32x4 p3 = *(const f32x4*)(b3g + 24 + 4*hi);
        b3c0 = p0 + p1; b3c1 = p2 + p3;
    }

    // rad ints, sigma order: one load serves JVP direction AND Hutchinson signs
    const int* rp = rad_g + ((size_t)row << 4);
    i32x4 c0 = *(const i32x4*)(rp + 4*hi);
    i32x4 c1 = *(const i32x4*)(rp + 8 + 4*hi);
    s16x8 pf = pconv(c0, c1);

    float ldet = 0.0f;

    for (int t = 0; t < NSTEP; ++t){
        const int* rpN = rp + (size_t)BATCH*16;
        const char* pHIt = pHI + t*512;

        // prefetch next step's ints (serve next pf AND next signs)
        i32x4 pn0 = {0,0,0,0}, pn1 = {0,0,0,0};
        if (t + 1 < NSTEP){
            pn0 = *(const i32x4*)(rpN + 4*hi);
            pn1 = *(const i32x4*)(rpN + 8 + 4*hi);
        }

        // ---- F init from FI table (broadcast b128 reads, b2 exact f32); T zero ----
        f32x16 F[4], T[4];
#pragma unroll
        for (int Mo = 0; Mo < 4; ++Mo){
            f32x4 f0 = *(const f32x4*)(pFI + Mo*128);
            f32x4 f1 = *(const f32x4*)(pFI + Mo*128 + 16);
            f32x4 f2 = *(const f32x4*)(pFI + Mo*128 + 32);
            f32x4 f3 = *(const f32x4*)(pFI + Mo*128 + 48);
            F[Mo] = (f32x16){f0[0],f0[1],f0[2],f0[3], f1[0],f1[1],f1[2],f1[3],
                             f2[0],f2[1],f2[2],f2[3], f3[0],f3[1],f3[2],f3[3]};
            T[Mo] = Z16;
        }

        // ---- L1: tt (prefetched pf) first, s-tiles (step-invariant, HI C-init),
        //      Euler-dependent xk0 LAST -> step t+1's L1 overlaps step t's tail ----
#pragma unroll
        for (int M = 0; M < 4; ++M){
            f32x4 g0 = *(const f32x4*)(pHIt + M*128);
            f32x4 g1 = *(const f32x4*)(pHIt + M*128 + 16);
            f32x4 g2 = *(const f32x4*)(pHIt + M*128 + 32);
            f32x4 g3 = *(const f32x4*)(pHIt + M*128 + 48);
            f32x16 hini = (f32x16){g0[0],g0[1],g0[2],g0[3], g1[0],g1[1],g1[2],g1[3],
                                   g2[0],g2[1],g2[2],g2[3], g3[0],g3[1],g3[2],g3[3]};

            s16x8 w10 = *(const s16x8*)(pW1 + M*6656);
            f32x16 tt = mfma32(w10, pf, Z16);
            f32x16 h  = mfma32(*(const s16x8*)(pW1 + M*6656 +  32), xk1, hini);
            h = mfma32(*(const s16x8*)(pW1 + M*6656 +  64), xk2, h);
            h = mfma32(*(const s16x8*)(pW1 + M*6656 +  96), xk3, h);
            h = mfma32(*(const s16x8*)(pW1 + M*6656 + 128), xk4, h);
            h = mfma32(w10, xk0, h);

            s16x8 bhA, bhB, btA, btB;
            pack_tr(h, tt, &bhA, &bhB, &btA, &btB);
#pragma unroll
            for (int Mo = 0; Mo < 4; ++Mo){
                s16x8 w2a = *(const s16x8*)(pW2 + Mo*9728 + (2*M)*32);
                F[Mo] = mfma32(w2a, bhA, F[Mo]);
                T[Mo] = mfma32(w2a, btA, T[Mo]);
                s16x8 w2b = *(const s16x8*)(pW2 + Mo*9728 + (2*M+1)*32);
                F[Mo] = mfma32(w2b, bhB, F[Mo]);
                T[Mo] = mfma32(w2b, btB, T[Mo]);
            }
        }

        // ---- L3 (W3 combined; rows 16..31 of A are zero -> acc r8..15 unused) ----
        f32x16 vf = {b3c0[0], b3c0[1], b3c0[2], b3c0[3],
                     b3c1[0], b3c1[1], b3c1[2], b3c1[3],
                     0,0,0,0,0,0,0,0};
        f32x16 vt = Z16;
#pragma unroll
        for (int M = 0; M < 4; ++M){
            s16x8 qhA, qhB, qtA, qtB;
            pack_tr(F[M], T[M], &qhA, &qhB, &qtA, &qtB);
            s16x8 w3a = *(const s16x8*)(pW3 + (2*M)*32);
            vf = mfma32(w3a, qhA, vf);
            vt = mfma32(w3a, qtA, vt);
            s16x8 w3b = *(const s16x8*)(pW3 + (2*M+1)*32);
            vf = mfma32(w3b, qhB, vf);
            vt = mfma32(w3b, qtB, vt);
        }

        // ---- Euler update (r0..3 -> dims 4hi+j, r4..7 -> dims 8+4hi+j) ----
        av0[0] += DELTA_F * vf[0]; av0[1] += DELTA_F * vf[1];
        av0[2] += DELTA_F * vf[2]; av0[3] += DELTA_F * vf[3];
        av1[0] += DELTA_F * vf[4]; av1[1] += DELTA_F * vf[5];
        av1[2] += DELTA_F * vf[6]; av1[3] += DELTA_F * vf[7];
        xk0 = mk_a();

        // ---- Hutchinson: signs from c0/c1 (dims 4hi.. and 8+4hi..) ----
        {
            int g0 = c0[0] ? 0 : (int)0x80000000u;
            int g1 = c0[1] ? 0 : (int)0x80000000u;
            int g2 = c0[2] ? 0 : (int)0x80000000u;
            int g3 = c0[3] ? 0 : (int)0x80000000u;
            int g4 = c1[0] ? 0 : (int)0x80000000u;
            int g5 = c1[1] ? 0 : (int)0x80000000u;
            int g6 = c1[2] ? 0 : (int)0x80000000u;
            int g7 = c1[3] ? 0 : (int)0x80000000u;
            float q0 = __int_as_float(__float_as_int(vt[0]) ^ g0);
            float q1 = __int_as_float(__float_as_int(vt[1]) ^ g1);
            float q2 = __int_as_float(__float_as_int(vt[2]) ^ g2);
            float q3 = __int_as_float(__float_as_int(vt[3]) ^ g3);
            float q4 = __int_as_float(__float_as_int(vt[4]) ^ g4);
            float q5 = __int_as_float(__float_as_int(vt[5]) ^ g5);
            float q6 = __int_as_float(__float_as_int(vt[6]) ^ g6);
            float q7 = __int_as_float(__float_as_int(vt[7]) ^ g7);
            float prod = ((q0 + q1) + (q2 + q3)) + ((q4 + q5) + (q6 + q7));
            unsigned pu = __float_as_uint(prod), pv = pu;
            pswap(pu, pv);                       // pu=[lo,lo], pv=[hi,hi]
            prod = __uint_as_float(pu) + __uint_as_float(pv);
            ldet -= DELTA_F * prod;
        }

        pf = pconv(pn0, pn1);
        c0 = pn0; c1 = pn1;
        rp = rpN;
    }

    // ---- finalize: logp = -0.5*|a|^2 - 8*ln(2pi) + ldet ----
    float asq = av0[0]*av0[0] + av0[1]*av0[1] + av0[2]*av0[2] + av0[3]*av0[3]
              + av1[0]*av1[0] + av1[1]*av1[1] + av1[2]*av1[2] + av1[3]*av1[3];
    {
        unsigned pu = __float_as_uint(asq), pv = pu;
        pswap(pu, pv);
        asq = __uint_as_float(pu) + __uint_as_float(pv);
    }
    if (hi == 0)
        out_g[row] = -0.5f*asq - 8.0f*LN2PI_F + ldet;
}

extern "C" void kernel_launch(void* const* d_in, const int* in_sizes, int n_in,
                              void* d_out, int out_size, void* d_ws, size_t ws_size,
                              hipStream_t stream)
{
    const float* s_g  = (const float*)d_in[0];
    const float* a0_g = (const float*)d_in[1];
    const int*   rad  = (const int*)  d_in[2];
    const float* W1   = (const float*)d_in[3];
    const float* b1   = (const float*)d_in[4];
    const float* W2   = (const float*)d_in[5];
    const float* b2   = (const float*)d_in[6];
    const float* W3   = (const float*)d_in[7];
    const float* b3   = (const float*)d_in[8];
    float* out = (float*)d_out;

    // opt-in to >64KB dynamic LDS (host-side attribute; capture-safe)
    hipFuncSetAttribute(reinterpret_cast<const void*>(cfm_kernel),
                        hipFuncAttributeMaxDynamicSharedMemorySize, LDS_BYTES);

    cfm_kernel<<<BATCH/RPB, NTHR, LDS_BYTES, stream>>>(
        s_g, a0_g, rad, W1, b1, W2, b2, W3, b3, out);
}

// Round 13
// 198.904 us; speedup vs baseline: 1.3627x; 1.3627x over previous
//
#include <hip/hip_runtime.h>
#include <hip/hip_bf16.h>
#include <stdint.h>

#define NSTEP   32
#define BATCH   65536
#define NTHR    512
#define RPB     256          /* rows per block = 8 waves x 32 */
#define DELTA_F (1.0f/32.0f)
#define LN2PI_F 1.83787706640934534f

// R32: byte-exact revert to R30 champion (199.1us).
// R31 lesson: the broad setprio(1)/(0) pair is a COMPILE-TIME scheduling
// region boundary. Removing it let the scheduler stretch live ranges past
// the 256-reg/wave ceiling -> scratch spill (WRITE 0.25->42MB, FETCH
// 76->704MB, 271us). Keep setprio exactly as-is: its value here is register-
// pressure containment, not runtime arbitration.
#define RB1 208              /* W1T row: 104 u16 (80 used: a0-15 sigma, s16-79) */
#define RB2 304              /* W2T row: 152 u16 (128 used: W2 sigma) */
#define RB3 272              /* W3C row: 136 u16 (128 used; rows 16..31 zero) */
#define OFF_W1 0             /* 128*208 = 26624 */
#define OFF_W2 26624         /* 128*304 = 38912 */
#define OFF_W3 65536         /* 32*272  = 8704  */
#define OFF_HI 74240         /* 32*4*2*16 f32 = 16384 */
#define OFF_FI 90624         /* 4*2*16 f32 = 512 */
#define LDS_BYTES 91136      /* 1 block/CU */

typedef __attribute__((ext_vector_type(8)))  short    s16x8;
typedef __attribute__((ext_vector_type(8)))  __bf16   bf16x8;
typedef __attribute__((ext_vector_type(4)))  float    f32x4;
typedef __attribute__((ext_vector_type(16))) float    f32x16;
typedef __attribute__((ext_vector_type(4)))  int      i32x4;
typedef __attribute__((ext_vector_type(4)))  unsigned u32x4;

#define Z16 ((f32x16){0,0,0,0,0,0,0,0,0,0,0,0,0,0,0,0})

static __device__ __forceinline__ f32x16 mfma32(s16x8 a, s16x8 b, f32x16 c){
    return __builtin_amdgcn_mfma_f32_32x32x16_bf16(
        __builtin_bit_cast(bf16x8, a), __builtin_bit_cast(bf16x8, b), c, 0, 0, 0);
}

static __device__ __forceinline__ unsigned short f2bf(float f){
    union { float f; unsigned u; } v; v.f = f;
    unsigned u = v.u + 0x7fffu + ((v.u >> 16) & 1u);   // RNE
    return (unsigned short)(u >> 16);
}

static __device__ __forceinline__ unsigned cvtpk(float lo, float hi){
    unsigned r;
    asm("v_cvt_pk_bf16_f32 %0, %1, %2" : "=v"(r) : "v"(lo), "v"(hi));
    return r;
}

// permlane32_swap (cold paths only: Hutchinson reduce + final asq)
static __device__ __forceinline__ void pswap(unsigned &a, unsigned &b){
    auto r = __builtin_amdgcn_permlane32_swap((int)a, (int)b, false, false);
    a = (unsigned)r[0]; b = (unsigned)r[1];
}

// sigma: swap bits 2 and 3 within each 16-block of the k index (self-inverse)
static __device__ __forceinline__ int sgk(int k){
    return (k & ~12) | ((k & 4) << 1) | ((k & 8) >> 1);
}

static __device__ __forceinline__ s16x8 pconv(i32x4 u0, i32x4 u1){
    const unsigned P = 0x3F80u, M = 0xBF80u;
    u32x4 d;
    d[0] = (u0[0] ? P : M) | ((u0[1] ? P : M) << 16);
    d[1] = (u0[2] ? P : M) | ((u0[3] ? P : M) << 16);
    d[2] = (u1[0] ? P : M) | ((u1[1] ? P : M) << 16);
    d[3] = (u1[2] ? P : M) | ((u1[3] ? P : M) << 16);
    return __builtin_bit_cast(s16x8, d);
}

// relu+mask pack of a 32x32 C-tile (16 f32) + tangent -> two k-tile B-frags
// each. NO cross-lane ops: sigma-staged weights absorb the lane->k mapping.
static __device__ __forceinline__ void pack_tr(const f32x16 h, const f32x16 tt,
        s16x8* bA, s16x8* bB, s16x8* tA, s16x8* tB){
    unsigned Ph[8], Pt[8];
#pragma unroll
    for (int q = 0; q < 8; ++q){
        float h0 = h[2*q], h1 = h[2*q+1];
        float r0 = h0 > 0.f ? h0 : 0.f,      r1 = h1 > 0.f ? h1 : 0.f;
        float s0 = h0 > 0.f ? tt[2*q] : 0.f, s1 = h1 > 0.f ? tt[2*q+1] : 0.f;
        Ph[q] = cvtpk(r0, r1);
        Pt[q] = cvtpk(s0, s1);
    }
    *bA = __builtin_bit_cast(s16x8, (u32x4){Ph[0], Ph[1], Ph[2], Ph[3]});
    *bB = __builtin_bit_cast(s16x8, (u32x4){Ph[4], Ph[5], Ph[6], Ph[7]});
    *tA = __builtin_bit_cast(s16x8, (u32x4){Pt[0], Pt[1], Pt[2], Pt[3]});
    *tB = __builtin_bit_cast(s16x8, (u32x4){Pt[4], Pt[5], Pt[6], Pt[7]});
}

__global__ __launch_bounds__(NTHR, 2)
void cfm_kernel(const float* __restrict__ s_g,
                const float* __restrict__ a0_g,
                const int*   __restrict__ rad_g,
                const float* __restrict__ W1g, const float* __restrict__ b1g,
                const float* __restrict__ W2g, const float* __restrict__ b2g,
                const float* __restrict__ W3g, const float* __restrict__ b3g,
                float* __restrict__ out_g)
{
    extern __shared__ char lds[];
    const int tid  = threadIdx.x;
    const int lane = tid & 63;
    const int wv   = tid >> 6;     // 0..7
    const int c32  = lane & 31;    // batch col within wave tile
    const int hi   = lane >> 5;    // k-half

    unsigned short* W1t = (unsigned short*)(lds + OFF_W1);
    unsigned short* W2t = (unsigned short*)(lds + OFF_W2);
    unsigned short* W3c = (unsigned short*)(lds + OFF_W3);
    float* HIt = (float*)(lds + OFF_HI);
    float* FIt = (float*)(lds + OFF_FI);

    // ------------- stage weights ONCE (sigma-permuted k-columns) -------------
    for (int idx = tid; idx < 128*104; idx += NTHR){
        int n = idx / 104, k = idx % 104;
        float v = 0.f;
        if (k < 16)       v = W1g[sgk(k)*128 + n];          // a-cols: sigma
        else if (k < 80)  v = W1g[k*128 + n];               // s-cols: identity
        W1t[n*104 + k] = f2bf(v);
    }
    for (int idx = tid; idx < 128*152; idx += NTHR){
        int n = idx / 152, k = idx % 152;
        float v = (k < 128) ? W2g[sgk(k)*128 + n] : 0.f;    // sigma
        W2t[n*152 + k] = f2bf(v);
    }
    for (int idx = tid; idx < 32*136; idx += NTHR){
        int m = idx / 136, k = idx % 136;
        float v = 0.f;
        if (m < 16 && k < 128){
            int pk = sgk(k);                                // sigma
            v = W3g[pk*32 + m] + W3g[pk*32 + 16 + m];
        }
        W3c[m*136 + k] = f2bf(v);
    }
    // HI table: [t][M][hi][16 r-ordered] = b1[m] + tmid(t)*W8[m], exact f32
    for (int idx = tid; idx < 32*4*2*16; idx += NTHR){
        int e  = idx & 15;
        int h2 = (idx >> 4) & 1;
        int M  = (idx >> 5) & 3;
        int t  = idx >> 7;
        int m  = 32*M + (e & 3) + 8*(e >> 2) + 4*h2;
        float tmid = ((float)t + 0.5f) * DELTA_F;
        HIt[idx] = b1g[m] + tmid * W1g[80*128 + m];
    }
    // FI table: [Mo][hi][16 r-ordered] = b2[m], exact f32
    if (tid < 128){
        int e  = tid & 15;
        int h2 = (tid >> 4) & 1;
        int Mo = tid >> 5;
        int m  = 32*Mo + (e & 3) + 8*(e >> 2) + 4*h2;
        FIt[tid] = b2g[m];
    }
    __syncthreads();

    // per-lane LDS bases (A-operand rows = c32; +hi*16 = k-half)
    const char* pW1 = lds + OFF_W1 + c32*RB1 + hi*16;
    const char* pW2 = lds + OFF_W2 + c32*RB2 + hi*16;
    const char* pW3 = lds + OFF_W3 + c32*RB3 + hi*16;
    const char* pHI = lds + OFF_HI + hi*64;   // + t*512 + M*128
    const char* pFI = lds + OFF_FI + hi*64;   // + Mo*128

    const int row = blockIdx.x * RPB + wv*32 + c32;

    // ---- X s-tiles (static over steps): tile K holds x[16K+8hi+j] ----
    const float* srow = s_g + (size_t)row * 64;
    s16x8 xk1, xk2, xk3, xk4;
    {
        auto mk_s = [&](int K)->s16x8{
            f32x4 u = *(const f32x4*)(srow + 16*(K-1) + 8*hi);
            f32x4 w = *(const f32x4*)(srow + 16*(K-1) + 8*hi + 4);
            return __builtin_bit_cast(s16x8, (u32x4){
                cvtpk(u[0],u[1]), cvtpk(u[2],u[3]), cvtpk(w[0],w[1]), cvtpk(w[2],w[3])});
        };
        xk1 = mk_s(1); xk2 = mk_s(2); xk3 = mk_s(3); xk4 = mk_s(4);
    }

    // a in f32: av0 = a[4hi+j], av1 = a[8+4hi+j]  (matches C-layout rows r0..3 / r4..7)
    f32x4 av0 = *(const f32x4*)(a0_g + (size_t)row*16 + 4*hi);
    f32x4 av1 = *(const f32x4*)(a0_g + (size_t)row*16 + 8 + 4*hi);

    // xk0 (a-tile B-frag): sigma-staged W1 a-cols -> pure in-lane pack
    auto mk_a = [&]()->s16x8{
        return __builtin_bit_cast(s16x8, (u32x4){
            cvtpk(av0[0],av0[1]), cvtpk(av0[2],av0[3]),
            cvtpk(av1[0],av1[1]), cvtpk(av1[2],av1[3])});
    };
    s16x8 xk0 = mk_a();

    // b3 combined (v_c + r), f32 per-lane: rows {4hi+j} and {8+4hi+j}
    f32x4 b3c0, b3c1;
    {
        f32x4 p0 = *(const f32x4*)(b3g + 4*hi);
        f32x4 p1 = *(const f32x4*)(b3g + 16 + 4*hi);
        f32x4 p2 = *(const f32x4*)(b3g + 8 + 4*hi);
        f32x4 p3 = *(const f32x4*)(b3g + 24 + 4*hi);
        b3c0 = p0 + p1; b3c1 = p2 + p3;
    }

    // rad ints, sigma order: one load serves JVP direction AND Hutchinson signs
    const int* rp = rad_g + ((size_t)row << 4);
    i32x4 c0 = *(const i32x4*)(rp + 4*hi);
    i32x4 c1 = *(const i32x4*)(rp + 8 + 4*hi);
    s16x8 pf = pconv(c0, c1);

    float ldet = 0.0f;

    for (int t = 0; t < NSTEP; ++t){
        const int* rpN = rp + (size_t)BATCH*16;
        const char* pHIt = pHI + t*512;

        // prefetch next step's ints (serve next pf AND next signs)
        i32x4 pn0 = {0,0,0,0}, pn1 = {0,0,0,0};
        if (t + 1 < NSTEP){
            pn0 = *(const i32x4*)(rpN + 4*hi);
            pn1 = *(const i32x4*)(rpN + 8 + 4*hi);
        }

        // ---- F init from FI table (broadcast b128 reads, b2 exact f32); T zero ----
        f32x16 F[4], T[4];
#pragma unroll
        for (int Mo = 0; Mo < 4; ++Mo){
            f32x4 f0 = *(const f32x4*)(pFI + Mo*128);
            f32x4 f1 = *(const f32x4*)(pFI + Mo*128 + 16);
            f32x4 f2 = *(const f32x4*)(pFI + Mo*128 + 32);
            f32x4 f3 = *(const f32x4*)(pFI + Mo*128 + 48);
            F[Mo] = (f32x16){f0[0],f0[1],f0[2],f0[3], f1[0],f1[1],f1[2],f1[3],
                             f2[0],f2[1],f2[2],f2[3], f3[0],f3[1],f3[2],f3[3]};
            T[Mo] = Z16;
        }

        __builtin_amdgcn_s_setprio(1);
        // ---- L1: tt (prefetched pf) first, s-tiles (step-invariant, HI C-init),
        //      Euler-dependent xk0 LAST -> step t+1's L1 overlaps step t's tail ----
#pragma unroll
        for (int M = 0; M < 4; ++M){
            f32x4 g0 = *(const f32x4*)(pHIt + M*128);
            f32x4 g1 = *(const f32x4*)(pHIt + M*128 + 16);
            f32x4 g2 = *(const f32x4*)(pHIt + M*128 + 32);
            f32x4 g3 = *(const f32x4*)(pHIt + M*128 + 48);
            f32x16 hini = (f32x16){g0[0],g0[1],g0[2],g0[3], g1[0],g1[1],g1[2],g1[3],
                                   g2[0],g2[1],g2[2],g2[3], g3[0],g3[1],g3[2],g3[3]};

            s16x8 w10 = *(const s16x8*)(pW1 + M*6656);
            f32x16 tt = mfma32(w10, pf, Z16);
            f32x16 h  = mfma32(*(const s16x8*)(pW1 + M*6656 +  32), xk1, hini);
            h = mfma32(*(const s16x8*)(pW1 + M*6656 +  64), xk2, h);
            h = mfma32(*(const s16x8*)(pW1 + M*6656 +  96), xk3, h);
            h = mfma32(*(const s16x8*)(pW1 + M*6656 + 128), xk4, h);
            h = mfma32(w10, xk0, h);

            s16x8 bhA, bhB, btA, btB;
            pack_tr(h, tt, &bhA, &bhB, &btA, &btB);
#pragma unroll
            for (int Mo = 0; Mo < 4; ++Mo){
                s16x8 w2a = *(const s16x8*)(pW2 + Mo*9728 + (2*M)*32);
                F[Mo] = mfma32(w2a, bhA, F[Mo]);
                T[Mo] = mfma32(w2a, btA, T[Mo]);
                s16x8 w2b = *(const s16x8*)(pW2 + Mo*9728 + (2*M+1)*32);
                F[Mo] = mfma32(w2b, bhB, F[Mo]);
                T[Mo] = mfma32(w2b, btB, T[Mo]);
            }
        }

        // ---- L3 (W3 combined; rows 16..31 of A are zero -> acc r8..15 unused) ----
        f32x16 vf = {b3c0[0], b3c0[1], b3c0[2], b3c0[3],
                     b3c1[0], b3c1[1], b3c1[2], b3c1[3],
                     0,0,0,0,0,0,0,0};
        f32x16 vt = Z16;
#pragma unroll
        for (int M = 0; M < 4; ++M){
            s16x8 qhA, qhB, qtA, qtB;
            pack_tr(F[M], T[M], &qhA, &qhB, &qtA, &qtB);
            s16x8 w3a = *(const s16x8*)(pW3 + (2*M)*32);
            vf = mfma32(w3a, qhA, vf);
            vt = mfma32(w3a, qtA, vt);
            s16x8 w3b = *(const s16x8*)(pW3 + (2*M+1)*32);
            vf = mfma32(w3b, qhB, vf);
            vt = mfma32(w3b, qtB, vt);
        }
        __builtin_amdgcn_s_setprio(0);

        // ---- Euler update (r0..3 -> dims 4hi+j, r4..7 -> dims 8+4hi+j) ----
        av0[0] += DELTA_F * vf[0]; av0[1] += DELTA_F * vf[1];
        av0[2] += DELTA_F * vf[2]; av0[3] += DELTA_F * vf[3];
        av1[0] += DELTA_F * vf[4]; av1[1] += DELTA_F * vf[5];
        av1[2] += DELTA_F * vf[6]; av1[3] += DELTA_F * vf[7];
        xk0 = mk_a();

        // ---- Hutchinson: signs from c0/c1 (dims 4hi.. and 8+4hi..) ----
        {
            int g0 = c0[0] ? 0 : (int)0x80000000u;
            int g1 = c0[1] ? 0 : (int)0x80000000u;
            int g2 = c0[2] ? 0 : (int)0x80000000u;
            int g3 = c0[3] ? 0 : (int)0x80000000u;
            int g4 = c1[0] ? 0 : (int)0x80000000u;
            int g5 = c1[1] ? 0 : (int)0x80000000u;
            int g6 = c1[2] ? 0 : (int)0x80000000u;
            int g7 = c1[3] ? 0 : (int)0x80000000u;
            float q0 = __int_as_float(__float_as_int(vt[0]) ^ g0);
            float q1 = __int_as_float(__float_as_int(vt[1]) ^ g1);
            float q2 = __int_as_float(__float_as_int(vt[2]) ^ g2);
            float q3 = __int_as_float(__float_as_int(vt[3]) ^ g3);
            float q4 = __int_as_float(__float_as_int(vt[4]) ^ g4);
            float q5 = __int_as_float(__float_as_int(vt[5]) ^ g5);
            float q6 = __int_as_float(__float_as_int(vt[6]) ^ g6);
            float q7 = __int_as_float(__float_as_int(vt[7]) ^ g7);
            float prod = ((q0 + q1) + (q2 + q3)) + ((q4 + q5) + (q6 + q7));
            unsigned pu = __float_as_uint(prod), pv = pu;
            pswap(pu, pv);                       // pu=[lo,lo], pv=[hi,hi]
            prod = __uint_as_float(pu) + __uint_as_float(pv);
            ldet -= DELTA_F * prod;
        }

        pf = pconv(pn0, pn1);
        c0 = pn0; c1 = pn1;
        rp = rpN;
    }

    // ---- finalize: logp = -0.5*|a|^2 - 8*ln(2pi) + ldet ----
    float asq = av0[0]*av0[0] + av0[1]*av0[1] + av0[2]*av0[2] + av0[3]*av0[3]
              + av1[0]*av1[0] + av1[1]*av1[1] + av1[2]*av1[2] + av1[3]*av1[3];
    {
        unsigned pu = __float_as_uint(asq), pv = pu;
        pswap(pu, pv);
        asq = __uint_as_float(pu) + __uint_as_float(pv);
    }
    if (hi == 0)
        out_g[row] = -0.5f*asq - 8.0f*LN2PI_F + ldet;
}

extern "C" void kernel_launch(void* const* d_in, const int* in_sizes, int n_in,
                              void* d_out, int out_size, void* d_ws, size_t ws_size,
                              hipStream_t stream)
{
    const float* s_g  = (const float*)d_in[0];
    const float* a0_g = (const float*)d_in[1];
    const int*   rad  = (const int*)  d_in[2];
    const float* W1   = (const float*)d_in[3];
    const float* b1   = (const float*)d_in[4];
    const float* W2   = (const float*)d_in[5];
    const float* b2   = (const float*)d_in[6];
    const float* W3   = (const float*)d_in[7];
    const float* b3   = (const float*)d_in[8];
    float* out = (float*)d_out;

    // opt-in to >64KB dynamic LDS (host-side attribute; capture-safe)
    hipFuncSetAttribute(reinterpret_cast<const void*>(cfm_kernel),
                        hipFuncAttributeMaxDynamicSharedMemorySize, LDS_BYTES);

    cfm_kernel<<<BATCH/RPB, NTHR, LDS_BYTES, stream>>>(
        s_g, a0_g, rad, W1, b1, W2, b2, W3, b3, out);
}